// Round 6
// baseline (214.878 us; speedup 1.0000x reference)
//
#include <hip/hip_runtime.h>

// B=4, H=W=64, N=4096, C=512, HEAD=8, dh=64, SR=4, Nk=256
// Split-bf16: val = hi + lo (both bf16). 3-term product drops only lo*lo (~4e-6 rel).

typedef __bf16 bf16x8 __attribute__((ext_vector_type(8)));
typedef float f32x4 __attribute__((ext_vector_type(4)));

__device__ __forceinline__ ushort f2bf(float v) {
  uint u = __float_as_uint(v);
  return (ushort)((u + 0x7FFFu + ((u >> 16) & 1u)) >> 16);
}
__device__ __forceinline__ float bf2f(ushort h) {
  return __uint_as_float((uint)h << 16);
}
__device__ __forceinline__ void gload16(const void* g, void* l) {
  __builtin_amdgcn_global_load_lds(
      (const __attribute__((address_space(1))) void*)g,
      (__attribute__((address_space(3))) void*)l, 16, 0, 0);
}
// bijective XCD swizzle for nwg % 8 == 0: work-ids contiguous per XCD
__device__ __forceinline__ int xcd_swz(int bid, int nwg) {
  int cpx = nwg >> 3;
  return (bid & 7) * cpx + (bid >> 3);
}

// ---------------- fused prep: convert x, W's, Wsr, biases ----------------
__global__ __launch_bounds__(256) void prep_kernel(
    const float* __restrict__ x, const float* __restrict__ Wq,
    const float* __restrict__ Wp, const float* __restrict__ Wk,
    const float* __restrict__ Wv, const float* __restrict__ Wsr,
    const float* __restrict__ bk, const float* __restrict__ bv,
    ushort* __restrict__ xq, ushort* __restrict__ Wq_,
    ushort* __restrict__ Wp_, ushort* __restrict__ Wkv_,
    ushort* __restrict__ Wsr_, float* __restrict__ bkv) {
  __shared__ float t[32][33];
  int bid = blockIdx.x, tid = threadIdx.x;
  if (bid < 4096 + 512) {
    const float* src;
    ushort* dst;
    int gid;
    if (bid < 4096) {  // x -> x' split
      src = x; dst = xq; gid = bid * 256 + tid;
    } else {
      int z = (bid - 4096) >> 7;
      src = (z == 0) ? Wq : (z == 1) ? Wp : (z == 2) ? Wk : Wv;
      dst = (z == 0) ? Wq_ : (z == 1) ? Wp_ : (z == 2) ? Wkv_ : (Wkv_ + 512 * 1024);
      gid = ((bid - 4096) & 127) * 256 + tid;
    }
    int row = gid >> 6, c8 = (gid & 63) << 3;
    float4 a = *(const float4*)(src + (size_t)row * 512 + c8);
    float4 b = *(const float4*)(src + (size_t)row * 512 + c8 + 4);
    ushort h[8], l[8];
    float vv[8] = {a.x, a.y, a.z, a.w, b.x, b.y, b.z, b.w};
#pragma unroll
    for (int e = 0; e < 8; ++e) { h[e] = f2bf(vv[e]); l[e] = f2bf(vv[e] - bf2f(h[e])); }
    uint4 hp, lp;
    hp.x = h[0] | ((uint)h[1] << 16); hp.y = h[2] | ((uint)h[3] << 16);
    hp.z = h[4] | ((uint)h[5] << 16); hp.w = h[6] | ((uint)h[7] << 16);
    lp.x = l[0] | ((uint)l[1] << 16); lp.y = l[2] | ((uint)l[3] << 16);
    lp.z = l[4] | ((uint)l[5] << 16); lp.w = l[6] | ((uint)l[7] << 16);
    *(uint4*)(dst + (size_t)row * 1024 + c8) = hp;
    *(uint4*)(dst + (size_t)row * 1024 + 512 + c8) = lp;
  } else if (bid < 4096 + 512 + 4096) {  // Wsr transpose+split
    int tb = bid - 4608;
    int z = tb >> 8, rem = tb & 255;
    int ci0 = (rem >> 4) << 5, co0 = (rem & 15) << 5;
    int tx = tid & 31, ty = tid >> 5;
#pragma unroll
    for (int i = 0; i < 32; i += 8)
      t[ty + i][tx] = Wsr[((size_t)z * 512 + ci0 + ty + i) * 512 + co0 + tx];
    __syncthreads();
#pragma unroll
    for (int i = 0; i < 32; i += 8) {
      float v = t[tx][ty + i];
      int co = co0 + ty + i, ci = ci0 + tx;
      ushort h = f2bf(v), l = f2bf(v - bf2f(h));
      Wsr_[((size_t)z * 512 + co) * 1024 + ci] = h;
      Wsr_[((size_t)z * 512 + co) * 1024 + 512 + ci] = l;
    }
  } else {  // bias concat
    bkv[tid] = bk[tid]; bkv[tid + 256] = bk[tid + 256];
    bkv[tid + 512] = bv[tid]; bkv[tid + 768] = bv[tid + 256];
  }
}

// ---------------- MFMA GEMM body (m97 structure), LDS passed in ----------------
// A',B' split-bf16 [rows][1024]; logical K'=1536.
// EPI=0: C fp32 [M][N] + bias. EPI=1: q-split per-head layout + scale 0.125.
template <int EPI>
__device__ __forceinline__ void gemm_body(
    const ushort* __restrict__ A, const ushort* __restrict__ Bw,
    const float* __restrict__ bias, float* __restrict__ C,
    ushort* __restrict__ Qs, int N, int bx, int by,
    ushort* As, ushort* Bs) {
  int tid = threadIdx.x;
  int lane = tid & 63, w = tid >> 6;
  int wr = w >> 1, wc = w & 1;
  int l15 = lane & 15, g = lane >> 4;
  int srow = lane >> 3;
  int scol = (lane & 7) ^ srow;  // pre-swizzled source block

  const ushort* aBase = A + (size_t)(by * 128 + w * 32 + srow) * 1024 + scol * 8;
  const ushort* bBase = Bw + (size_t)(bx * 128 + w * 32 + srow) * 1024 + scol * 8;
  ushort* aDst = &As[w * 32 * 64];
  ushort* bDst = &Bs[w * 32 * 64];

  f32x4 acc[4][4];
#pragma unroll
  for (int i = 0; i < 4; ++i)
#pragma unroll
    for (int j = 0; j < 4; ++j) acc[i][j] = (f32x4){0.f, 0.f, 0.f, 0.f};

  for (int ks = 0; ks < 24; ++ks) {
    int kk = ks * 64;
    int ap = kk - (kk >= 1024 ? 1024 : 0);
    int bp = kk - (kk >= 512 ? 512 : 0);
#pragma unroll
    for (int t = 0; t < 4; ++t) {
      gload16(aBase + (size_t)t * 8192 + ap, aDst + t * 512);
      gload16(bBase + (size_t)t * 8192 + bp, bDst + t * 512);
    }
    __syncthreads();
#pragma unroll
    for (int kk2 = 0; kk2 < 2; ++kk2) {
      int rb = kk2 * 4 + g;
      bf16x8 af[4], bg[4];
#pragma unroll
      for (int i = 0; i < 4; ++i) {
        int row = wr * 64 + i * 16 + l15;
        af[i] = *(const bf16x8*)&As[row * 64 + ((rb ^ (row & 7)) << 3)];
      }
#pragma unroll
      for (int j = 0; j < 4; ++j) {
        int col = wc * 64 + j * 16 + l15;
        bg[j] = *(const bf16x8*)&Bs[col * 64 + ((rb ^ (col & 7)) << 3)];
      }
#pragma unroll
      for (int i = 0; i < 4; ++i)
#pragma unroll
        for (int j = 0; j < 4; ++j)
          acc[i][j] = __builtin_amdgcn_mfma_f32_16x16x32_bf16(af[i], bg[j], acc[i][j], 0, 0, 0);
    }
    __syncthreads();
  }

  if (EPI == 0) {
#pragma unroll
    for (int j = 0; j < 4; ++j) {
      int col = bx * 128 + wc * 64 + j * 16 + l15;
      float bj = bias ? bias[col] : 0.f;
#pragma unroll
      for (int i = 0; i < 4; ++i) {
        int row0 = by * 128 + wr * 64 + i * 16 + g * 4;
#pragma unroll
        for (int r = 0; r < 4; ++r)
          C[(size_t)(row0 + r) * N + col] = acc[i][j][r] + bj;
      }
    }
  } else {
#pragma unroll
    for (int j = 0; j < 4; ++j) {
      int col = bx * 128 + wc * 64 + j * 16 + l15;  // < 512
      float bj = bias[col];
      int hh = col >> 6, d = col & 63;
#pragma unroll
      for (int i = 0; i < 4; ++i) {
        int row0 = by * 128 + wr * 64 + i * 16 + g * 4;
#pragma unroll
        for (int r = 0; r < 4; ++r) {
          float v = (acc[i][j][r] + bj) * 0.125f;
          ushort h = f2bf(v), lo = f2bf(v - bf2f(h));
          size_t base = ((size_t)(row0 + r) * 8 + hh) * 128 + d;
          Qs[base] = h;
          Qs[base + 64] = lo;
        }
      }
    }
  }
}

// fused q-proj (512 work-ids) + kv-proj (64 work-ids), XCD-swizzled
__global__ __launch_bounds__(256) void proj_fused_kernel(
    const ushort* __restrict__ xq, const ushort* __restrict__ Wq_,
    const float* __restrict__ bq, ushort* __restrict__ Qs,
    const ushort* __restrict__ xkv_, const ushort* __restrict__ Wkv_,
    const float* __restrict__ bkv, float* __restrict__ kvb) {
  __shared__ __align__(16) ushort As[128 * 64];
  __shared__ __align__(16) ushort Bs[128 * 64];
  int bid = xcd_swz(blockIdx.x, 576);
  if (bid < 512)
    gemm_body<1>(xq, Wq_, bq, nullptr, Qs, 512, bid & 3, bid >> 2, As, Bs);
  else {
    int b2 = bid - 512;
    gemm_body<0>(xkv_, Wkv_, bkv, kvb, nullptr, 1024, b2 & 7, b2 >> 3, As, Bs);
  }
}

// out-proj, XCD-swizzled
__global__ __launch_bounds__(256) void gemm_out_kernel(
    const ushort* __restrict__ A, const ushort* __restrict__ Bw,
    const float* __restrict__ bias, float* __restrict__ C) {
  __shared__ __align__(16) ushort As[128 * 64];
  __shared__ __align__(16) ushort Bs[128 * 64];
  int bid = xcd_swz(blockIdx.x, 512);
  gemm_body<0>(A, Bw, bias, C, nullptr, 512, bid & 3, bid >> 2, As, Bs);
}

// ---------------- conv as split-16 MFMA GEMM (one tap per z) ----------------
__global__ __launch_bounds__(256) void conv_mfma_kernel(
    const ushort* __restrict__ xq, const ushort* __restrict__ Wsr_,
    float* __restrict__ part) {
  __shared__ __align__(16) ushort As[128 * 64];
  __shared__ __align__(16) ushort Bs[128 * 64];
  int bid = xcd_swz(blockIdx.x, 512);
  int bx = bid & 3, by = (bid >> 2) & 7, z = bid >> 5;
  int kh = z >> 2, kw = z & 3;
  int tid = threadIdx.x;
  int lane = tid & 63, w = tid >> 6;
  int wr = w >> 1, wc = w & 1;
  int l15 = lane & 15, g = lane >> 4;
  int srow = lane >> 3;
  int scol = (lane & 7) ^ srow;

  const ushort* aBase[4];
#pragma unroll
  for (int t = 0; t < 4; ++t) {
    int gm = by * 128 + w * 32 + t * 8 + srow;
    int xr = (gm >> 8) * 4096 + ((((gm >> 4) & 15) << 2) + kh) * 64 +
             ((gm & 15) << 2) + kw;
    aBase[t] = xq + (size_t)xr * 1024 + scol * 8;
  }
  const ushort* bBase =
      Wsr_ + ((size_t)z * 512 + bx * 128 + w * 32 + srow) * 1024 + scol * 8;
  ushort* aDst = &As[w * 32 * 64];
  ushort* bDst = &Bs[w * 32 * 64];

  f32x4 acc[4][4];
#pragma unroll
  for (int i = 0; i < 4; ++i)
#pragma unroll
    for (int j = 0; j < 4; ++j) acc[i][j] = (f32x4){0.f, 0.f, 0.f, 0.f};

  for (int ks = 0; ks < 24; ++ks) {
    int kk = ks * 64;
    int ap = kk - (kk >= 1024 ? 1024 : 0);
    int bp = kk - (kk >= 512 ? 512 : 0);
#pragma unroll
    for (int t = 0; t < 4; ++t) {
      gload16(aBase[t] + ap, aDst + t * 512);
      gload16(bBase + (size_t)t * 8192 + bp, bDst + t * 512);
    }
    __syncthreads();
#pragma unroll
    for (int kk2 = 0; kk2 < 2; ++kk2) {
      int rb = kk2 * 4 + g;
      bf16x8 af[4], bg[4];
#pragma unroll
      for (int i = 0; i < 4; ++i) {
        int row = wr * 64 + i * 16 + l15;
        af[i] = *(const bf16x8*)&As[row * 64 + ((rb ^ (row & 7)) << 3)];
      }
#pragma unroll
      for (int j = 0; j < 4; ++j) {
        int col = wc * 64 + j * 16 + l15;
        bg[j] = *(const bf16x8*)&Bs[col * 64 + ((rb ^ (col & 7)) << 3)];
      }
#pragma unroll
      for (int i = 0; i < 4; ++i)
#pragma unroll
        for (int j = 0; j < 4; ++j)
          acc[i][j] = __builtin_amdgcn_mfma_f32_16x16x32_bf16(af[i], bg[j], acc[i][j], 0, 0, 0);
    }
    __syncthreads();
  }

  float* Cp = part + (size_t)z * 524288;
#pragma unroll
  for (int j = 0; j < 4; ++j) {
    int col = bx * 128 + wc * 64 + j * 16 + l15;
#pragma unroll
    for (int i = 0; i < 4; ++i) {
      int row0 = by * 128 + wr * 64 + i * 16 + g * 4;
#pragma unroll
      for (int r = 0; r < 4; ++r)
        Cp[(size_t)(row0 + r) * 512 + col] = acc[i][j][r];
    }
  }
}

// ---------------- partial-sum(16) + bias + LayerNorm -> split-bf16 ----------------
__global__ __launch_bounds__(256) void ln_kernel(
    const float* __restrict__ part, const float* __restrict__ bsr,
    const float* __restrict__ gamma, const float* __restrict__ beta,
    ushort* __restrict__ xkv_) {
  int row = blockIdx.x;
  int t = threadIdx.x;
  float v0 = bsr[t], v1 = bsr[t + 256];
  for (int p = 0; p < 16; ++p) {
    v0 += part[(size_t)p * 524288 + (size_t)row * 512 + t];
    v1 += part[(size_t)p * 524288 + (size_t)row * 512 + t + 256];
  }
  float s = v0 + v1, sq = v0 * v0 + v1 * v1;
#pragma unroll
  for (int o = 1; o < 64; o <<= 1) {
    s += __shfl_xor(s, o);
    sq += __shfl_xor(sq, o);
  }
  __shared__ float red[8];
  int wv = t >> 6;
  if ((t & 63) == 0) { red[wv] = s; red[4 + wv] = sq; }
  __syncthreads();
  s = red[0] + red[1] + red[2] + red[3];
  sq = red[4] + red[5] + red[6] + red[7];
  float mu = s * (1.0f / 512.0f);
  float var = sq * (1.0f / 512.0f) - mu * mu;
  float rs = rsqrtf(var + 1e-5f);
  float y0 = (v0 - mu) * rs * gamma[t] + beta[t];
  float y1 = (v1 - mu) * rs * gamma[t + 256] + beta[t + 256];
  ushort h0 = f2bf(y0), h1 = f2bf(y1);
  xkv_[(size_t)row * 1024 + t] = h0;
  xkv_[(size_t)row * 1024 + t + 256] = h1;
  xkv_[(size_t)row * 1024 + 512 + t] = f2bf(y0 - bf2f(h0));
  xkv_[(size_t)row * 1024 + 512 + t + 256] = f2bf(y1 - bf2f(h1));
}

// ---------------- kv prep: kvb fp32 -> Kq split [bh][256][128], Vt split [bh][64][512]
__global__ __launch_bounds__(256) void kvprep_kernel(
    const float* __restrict__ kvb, ushort* __restrict__ Kq,
    ushort* __restrict__ Vt) {
  int gid = blockIdx.x * 256 + threadIdx.x;  // 131072
  int row = gid >> 7, c8 = (gid & 127) << 3;
  int b = row >> 8, kk = row & 255;
  float4 a = *(const float4*)(kvb + (size_t)row * 1024 + c8);
  float4 bb = *(const float4*)(kvb + (size_t)row * 1024 + c8 + 4);
  float vv[8] = {a.x, a.y, a.z, a.w, bb.x, bb.y, bb.z, bb.w};
  ushort h[8], l[8];
#pragma unroll
  for (int e = 0; e < 8; ++e) { h[e] = f2bf(vv[e]); l[e] = f2bf(vv[e] - bf2f(h[e])); }
  if (c8 < 512) {
    int hh = c8 >> 6, d = c8 & 63;
    uint4 hp, lp;
    hp.x = h[0] | ((uint)h[1] << 16); hp.y = h[2] | ((uint)h[3] << 16);
    hp.z = h[4] | ((uint)h[5] << 16); hp.w = h[6] | ((uint)h[7] << 16);
    lp.x = l[0] | ((uint)l[1] << 16); lp.y = l[2] | ((uint)l[3] << 16);
    lp.z = l[4] | ((uint)l[5] << 16); lp.w = l[6] | ((uint)l[7] << 16);
    size_t base = ((size_t)((b * 8 + hh) * 256) + kk) * 128 + d;
    *(uint4*)(Kq + base) = hp;
    *(uint4*)(Kq + base + 64) = lp;
  } else {
    int c = c8 - 512;
    int hh = c >> 6, d0 = c & 63;
#pragma unroll
    for (int jj = 0; jj < 8; ++jj) {
      size_t base = ((size_t)((b * 8 + hh) * 64) + d0 + jj) * 512 + kk;
      Vt[base] = h[jj];
      Vt[base + 256] = l[jj];
    }
  }
}

// ---------------- MFMA flash attention ----------------
__global__ __launch_bounds__(256) void attn_kernel(
    const ushort* __restrict__ Qs, const ushort* __restrict__ Kq,
    const ushort* __restrict__ Vt, ushort* __restrict__ attno) {
  __shared__ __align__(16) char arena[16384 + 16384 + 8192];
  ushort* KsL = (ushort*)arena;            // [64 kk][128: hi|lo], swizzled
  ushort* VtL = (ushort*)(arena + 16384);  // [64 d][128: hi|lo kk], swizzled
  ushort* PL = (ushort*)(arena + 32768);   // [64 q][64 kk] bf16, swizzled
  float* ob = (float*)arena;               // [64 d][68 q] epilogue alias

  int tid = threadIdx.x;
  int qb = blockIdx.x, h = blockIdx.y, b = blockIdx.z;
  int n0 = qb * 64, bh = b * 8 + h;
  int lane = tid & 63, w = tid >> 6;
  int q15 = lane & 15, g = lane >> 4;
  int qrow = w * 16 + q15;

  const ushort* qptr = Qs + ((size_t)(b * 4096 + n0 + qrow) * 8 + h) * 128;
  bf16x8 qf[2][2];
#pragma unroll
  for (int s = 0; s < 2; ++s)
#pragma unroll
    for (int kb = 0; kb < 2; ++kb)
      qf[s][kb] = *(const bf16x8*)(qptr + s * 64 + kb * 32 + g * 8);

  f32x4 accO[4];
#pragma unroll
  for (int t = 0; t < 4; ++t) accO[t] = (f32x4){0.f, 0.f, 0.f, 0.f};
  float m = -1e30f, l = 0.f;

  const ushort* kbase = Kq + (size_t)bh * 256 * 128;
  const ushort* vbase = Vt + (size_t)bh * 64 * 512;

  for (int c = 0; c < 4; ++c) {
    __syncthreads();
#pragma unroll
    for (int i = 0; i < 4; ++i) {
      int idx = tid + i * 256;
      int r = idx >> 4, blk = idx & 15;
      uint4 kv4 = *(const uint4*)(kbase + (size_t)(c * 64 + r) * 128 + blk * 8);
      *(uint4*)&KsL[r * 128 + ((blk ^ (r & 7)) << 3)] = kv4;
      uint4 vv4 = *(const uint4*)(vbase + (size_t)r * 512 + ((blk >> 3) << 8) +
                                  c * 64 + ((blk & 7) << 3));
      *(uint4*)&VtL[r * 128 + ((blk ^ (r & 7)) << 3)] = vv4;
    }
    __syncthreads();

    f32x4 accS[4];
#pragma unroll
    for (int t = 0; t < 4; ++t) accS[t] = (f32x4){0.f, 0.f, 0.f, 0.f};
#pragma unroll
    for (int kb = 0; kb < 2; ++kb) {
      bf16x8 ak[4];
#pragma unroll
      for (int t = 0; t < 4; ++t) {
        int kkr = t * 16 + q15;
        ak[t] = *(const bf16x8*)&KsL[kkr * 128 + (((kb * 4 + g) ^ (kkr & 7)) << 3)];
      }
#pragma unroll
      for (int t = 0; t < 4; ++t)
        accS[t] = __builtin_amdgcn_mfma_f32_16x16x32_bf16(ak[t], qf[0][kb], accS[t], 0, 0, 0);
#pragma unroll
      for (int t = 0; t < 4; ++t)
        accS[t] = __builtin_amdgcn_mfma_f32_16x16x32_bf16(ak[t], qf[1][kb], accS[t], 0, 0, 0);
#pragma unroll
      for (int t = 0; t < 4; ++t) {
        int kkr = t * 16 + q15;
        bf16x8 al = *(const bf16x8*)&KsL[kkr * 128 + (((8 + kb * 4 + g) ^ (kkr & 7)) << 3)];
        accS[t] = __builtin_amdgcn_mfma_f32_16x16x32_bf16(al, qf[0][kb], accS[t], 0, 0, 0);
      }
    }

    float mx = -1e30f;
#pragma unroll
    for (int t = 0; t < 4; ++t)
#pragma unroll
      for (int r = 0; r < 4; ++r) mx = fmaxf(mx, accS[t][r]);
    mx = fmaxf(mx, __shfl_xor(mx, 16));
    mx = fmaxf(mx, __shfl_xor(mx, 32));
    float mn = fmaxf(m, mx);
    float fac = __expf(m - mn);
    m = mn;
    float sum = 0.f;
    ushort ph[4][4];
#pragma unroll
    for (int t = 0; t < 4; ++t)
#pragma unroll
      for (int r = 0; r < 4; ++r) {
        float p = __expf(accS[t][r] - mn);
        ushort hp = f2bf(p);
        ph[t][r] = hp;
        sum += bf2f(hp);
      }
    sum += __shfl_xor(sum, 16);
    sum += __shfl_xor(sum, 32);
    l = l * fac + sum;
#pragma unroll
    for (int t = 0; t < 4; ++t) {
      accO[t][0] *= fac; accO[t][1] *= fac; accO[t][2] *= fac; accO[t][3] *= fac;
    }
#pragma unroll
    for (int t = 0; t < 4; ++t)
#pragma unroll
      for (int rp = 0; rp < 4; rp += 2) {
        uint u = ph[t][rp] | ((uint)ph[t][rp + 1] << 16);
        int kkl = t * 16 + g * 4 + rp;
        int blk = kkl >> 3, off = kkl & 7;
        *(uint*)((char*)PL + qrow * 128 + ((blk ^ (q15 & 7)) << 4) + off * 2) = u;
      }
    __syncthreads();

    bf16x8 pf[2];
#pragma unroll
    for (int kb = 0; kb < 2; ++kb)
      pf[kb] = *(const bf16x8*)((char*)PL + qrow * 128 + (((kb * 4 + g) ^ (q15 & 7)) << 4));
#pragma unroll
    for (int s = 0; s < 2; ++s)
#pragma unroll
      for (int kb = 0; kb < 2; ++kb)
#pragma unroll
        for (int t = 0; t < 4; ++t) {
          int d = t * 16 + q15;
          bf16x8 vf =
              *(const bf16x8*)&VtL[d * 128 + (((s * 8 + kb * 4 + g) ^ (d & 7)) << 3)];
          accO[t] = __builtin_amdgcn_mfma_f32_16x16x32_bf16(vf, pf[kb], accO[t], 0, 0, 0);
        }
  }

  float inv = 1.0f / l;
  __syncthreads();
#pragma unroll
  for (int t = 0; t < 4; ++t)
#pragma unroll
    for (int r = 0; r < 4; ++r)
      ob[(t * 16 + g * 4 + r) * 68 + qrow] = accO[t][r] * inv;
  __syncthreads();
#pragma unroll
  for (int i = 0; i < 2; ++i) {
    int idx = tid + i * 256;
    int qq = idx >> 3, d8 = (idx & 7) << 3;
    ushort hh[8], ll[8];
#pragma unroll
    for (int jj = 0; jj < 8; ++jj) {
      float v = ob[(d8 + jj) * 68 + qq];
      hh[jj] = f2bf(v);
      ll[jj] = f2bf(v - bf2f(hh[jj]));
    }
    uint4 hp, lp;
    hp.x = hh[0] | ((uint)hh[1] << 16); hp.y = hh[2] | ((uint)hh[3] << 16);
    hp.z = hh[4] | ((uint)hh[5] << 16); hp.w = hh[6] | ((uint)hh[7] << 16);
    lp.x = ll[0] | ((uint)ll[1] << 16); lp.y = ll[2] | ((uint)ll[3] << 16);
    lp.z = ll[4] | ((uint)ll[5] << 16); lp.w = ll[6] | ((uint)ll[7] << 16);
    size_t rowb = (size_t)(b * 4096 + n0 + qq) * 1024 + h * 64 + d8;
    *(uint4*)(attno + rowb) = hp;
    *(uint4*)(attno + rowb + 512) = lp;
  }
}

// ---------------- launch ----------------
extern "C" void kernel_launch(void* const* d_in, const int* in_sizes, int n_in,
                              void* d_out, int out_size, void* d_ws, size_t ws_size,
                              hipStream_t stream) {
  const float* x     = (const float*)d_in[0];
  const float* Wq    = (const float*)d_in[1];
  const float* bq    = (const float*)d_in[2];
  const float* Wk    = (const float*)d_in[3];
  const float* bk    = (const float*)d_in[4];
  const float* Wv    = (const float*)d_in[5];
  const float* bv    = (const float*)d_in[6];
  const float* Wp    = (const float*)d_in[7];
  const float* bp    = (const float*)d_in[8];
  const float* Wsr   = (const float*)d_in[9];
  const float* bsr   = (const float*)d_in[10];
  const float* gamma = (const float*)d_in[11];
  const float* beta  = (const float*)d_in[12];

  float* ws = (float*)d_ws;
  // regionA (8,388,608 fl): xq (dies after proj launch); then attno_
  ushort* xq     = (ushort*)ws;
  ushort* attno_ = (ushort*)ws;
  // regionB (8,388,608 fl): conv_part [16][1024][512] f32; then Qsplit
  float*  conv_part = ws + 8388608;
  ushort* Qsplit    = (ushort*)(ws + 8388608);
  // tail: Wsr_ (prep->conv), then kv chain
  ushort* Wsr_ = (ushort*)(ws + 16777216);
  float*  kvb  = ws + 16777216 + 4194304;   // after Wsr_ region? no overlap concerns:
  // Wsr_ occupies ws[16777216 .. 16777216+4194304) as ushort (8,388,608 us = 4,194,304 fl)
  // place kv chain AFTER it:
  kvb  = ws + 20971520;                     // 1,048,576 fl
  ushort* Kq   = (ushort*)(ws + 22020096);  // 1,048,576 us = 524,288 fl
  ushort* Vt   = (ushort*)(ws + 22544384);  // 1,048,576 us
  // weights + xkv_ + bkv
  ushort* Wq_  = (ushort*)(ws + 23068672);
  ushort* Wp_  = (ushort*)(ws + 23330816);
  ushort* Wkv_ = (ushort*)(ws + 23592960);
  ushort* xkv_ = (ushort*)(ws + 24117248);
  float*  bkv  = ws + 24641536;
  float* outp = (float*)d_out;

  prep_kernel<<<8705, 256, 0, stream>>>(x, Wq, Wp, Wk, Wv, Wsr, bk, bv,
                                        xq, Wq_, Wp_, Wkv_, Wsr_, bkv);
  conv_mfma_kernel<<<512, 256, 0, stream>>>(xq, Wsr_, conv_part);
  ln_kernel<<<1024, 256, 0, stream>>>(conv_part, bsr, gamma, beta, xkv_);
  proj_fused_kernel<<<576, 256, 0, stream>>>(xq, Wq_, bq, Qsplit, xkv_, Wkv_, bkv, kvb);
  kvprep_kernel<<<512, 256, 0, stream>>>(kvb, Kq, Vt);
  attn_kernel<<<dim3(64, 8, 4), 256, 0, stream>>>(Qsplit, Kq, Vt, attno_);
  gemm_out_kernel<<<512, 256, 0, stream>>>(attno_, Wp_, bp, outp);
}

// Round 7
// 185.794 us; speedup vs baseline: 1.1565x; 1.1565x over previous
//
#include <hip/hip_runtime.h>

// B=4, H=W=64, N=4096, C=512, HEAD=8, dh=64, SR=4, Nk=256
// Split-bf16: val = hi + lo (both bf16). 3-term product drops only lo*lo (~4e-6 rel).

typedef __bf16 bf16x8 __attribute__((ext_vector_type(8)));
typedef float f32x4 __attribute__((ext_vector_type(4)));

__device__ __forceinline__ ushort f2bf(float v) {
  uint u = __float_as_uint(v);
  return (ushort)((u + 0x7FFFu + ((u >> 16) & 1u)) >> 16);
}
__device__ __forceinline__ float bf2f(ushort h) {
  return __uint_as_float((uint)h << 16);
}
__device__ __forceinline__ void gload16(const void* g, void* l) {
  __builtin_amdgcn_global_load_lds(
      (const __attribute__((address_space(1))) void*)g,
      (__attribute__((address_space(3))) void*)l, 16, 0, 0);
}
// bijective XCD swizzle for nwg % 8 == 0: work-ids contiguous per XCD
__device__ __forceinline__ int xcd_swz(int bid, int nwg) {
  int cpx = nwg >> 3;
  return (bid & 7) * cpx + (bid >> 3);
}

// ---------------- fused prep: convert x, W's, Wsr, biases ----------------
__global__ __launch_bounds__(256) void prep_kernel(
    const float* __restrict__ x, const float* __restrict__ Wq,
    const float* __restrict__ Wp, const float* __restrict__ Wk,
    const float* __restrict__ Wv, const float* __restrict__ Wsr,
    const float* __restrict__ bk, const float* __restrict__ bv,
    ushort* __restrict__ xq, ushort* __restrict__ Wq_,
    ushort* __restrict__ Wp_, ushort* __restrict__ Wkv_,
    ushort* __restrict__ Wsr_, float* __restrict__ bkv) {
  __shared__ float t[32][33];
  int bid = blockIdx.x, tid = threadIdx.x;
  if (bid < 4096 + 512) {
    const float* src;
    ushort* dst;
    int gid;
    if (bid < 4096) {  // x -> x' split
      src = x; dst = xq; gid = bid * 256 + tid;
    } else {
      int z = (bid - 4096) >> 7;
      src = (z == 0) ? Wq : (z == 1) ? Wp : (z == 2) ? Wk : Wv;
      dst = (z == 0) ? Wq_ : (z == 1) ? Wp_ : (z == 2) ? Wkv_ : (Wkv_ + 512 * 1024);
      gid = ((bid - 4096) & 127) * 256 + tid;
    }
    int row = gid >> 6, c8 = (gid & 63) << 3;
    float4 a = *(const float4*)(src + (size_t)row * 512 + c8);
    float4 b = *(const float4*)(src + (size_t)row * 512 + c8 + 4);
    ushort h[8], l[8];
    float vv[8] = {a.x, a.y, a.z, a.w, b.x, b.y, b.z, b.w};
#pragma unroll
    for (int e = 0; e < 8; ++e) { h[e] = f2bf(vv[e]); l[e] = f2bf(vv[e] - bf2f(h[e])); }
    uint4 hp, lp;
    hp.x = h[0] | ((uint)h[1] << 16); hp.y = h[2] | ((uint)h[3] << 16);
    hp.z = h[4] | ((uint)h[5] << 16); hp.w = h[6] | ((uint)h[7] << 16);
    lp.x = l[0] | ((uint)l[1] << 16); lp.y = l[2] | ((uint)l[3] << 16);
    lp.z = l[4] | ((uint)l[5] << 16); lp.w = l[6] | ((uint)l[7] << 16);
    *(uint4*)(dst + (size_t)row * 1024 + c8) = hp;
    *(uint4*)(dst + (size_t)row * 1024 + 512 + c8) = lp;
  } else if (bid < 4096 + 512 + 4096) {  // Wsr transpose+split
    int tb = bid - 4608;
    int z = tb >> 8, rem = tb & 255;
    int ci0 = (rem >> 4) << 5, co0 = (rem & 15) << 5;
    int tx = tid & 31, ty = tid >> 5;
#pragma unroll
    for (int i = 0; i < 32; i += 8)
      t[ty + i][tx] = Wsr[((size_t)z * 512 + ci0 + ty + i) * 512 + co0 + tx];
    __syncthreads();
#pragma unroll
    for (int i = 0; i < 32; i += 8) {
      float v = t[tx][ty + i];
      int co = co0 + ty + i, ci = ci0 + tx;
      ushort h = f2bf(v), l = f2bf(v - bf2f(h));
      Wsr_[((size_t)z * 512 + co) * 1024 + ci] = h;
      Wsr_[((size_t)z * 512 + co) * 1024 + 512 + ci] = l;
    }
  } else {  // bias concat
    bkv[tid] = bk[tid]; bkv[tid + 256] = bk[tid + 256];
    bkv[tid + 512] = bv[tid]; bkv[tid + 768] = bv[tid + 256];
  }
}

// ---------------- MFMA GEMM body: double-buffered 2-phase K-loop ----------------
// A',B' split-bf16 [rows][1024]; logical K'=1536 (24 steps of 64).
// lds arena: 4 x 8192 ushorts = 64KB. buf k: A at k*16384, B at k*16384+8192.
// EPI=0: C fp32 [M][N] + bias. EPI=1: Qsplit per-head layout via coalesced LDS epilogue.
template <int EPI>
__device__ __forceinline__ void gemm_body(
    const ushort* __restrict__ A, const ushort* __restrict__ Bw,
    const float* __restrict__ bias, float* __restrict__ C,
    ushort* __restrict__ Qs, int N, int bx, int by, ushort* lds) {
  int tid = threadIdx.x;
  int lane = tid & 63, w = tid >> 6;
  int wr = w >> 1, wc = w & 1;
  int l15 = lane & 15, g = lane >> 4;
  int srow = lane >> 3;
  int scol = (lane & 7) ^ srow;  // pre-swizzled source block

  const ushort* aBase = A + (size_t)(by * 128 + w * 32 + srow) * 1024 + scol * 8;
  const ushort* bBase = Bw + (size_t)(bx * 128 + w * 32 + srow) * 1024 + scol * 8;

  f32x4 acc[4][4];
#pragma unroll
  for (int i = 0; i < 4; ++i)
#pragma unroll
    for (int j = 0; j < 4; ++j) acc[i][j] = (f32x4){0.f, 0.f, 0.f, 0.f};

#define STAGE_G(ks, buf)                                              \
  {                                                                   \
    int kk = (ks) * 64;                                               \
    int ap = kk - (kk >= 1024 ? 1024 : 0);                            \
    int bp = kk - (kk >= 512 ? 512 : 0);                              \
    ushort* aD = lds + (buf) * 16384 + w * 2048;                      \
    ushort* bD = lds + (buf) * 16384 + 8192 + w * 2048;               \
    _Pragma("unroll") for (int t = 0; t < 4; ++t) {                   \
      gload16(aBase + (size_t)t * 8192 + ap, aD + t * 512);           \
      gload16(bBase + (size_t)t * 8192 + bp, bD + t * 512);           \
    }                                                                 \
  }

#define COMPUTE_G(buf)                                                         \
  {                                                                            \
    const ushort* As = lds + (buf) * 16384;                                    \
    const ushort* Bs = As + 8192;                                              \
    _Pragma("unroll") for (int kk2 = 0; kk2 < 2; ++kk2) {                      \
      int rb = kk2 * 4 + g;                                                    \
      bf16x8 af[4], bg[4];                                                     \
      _Pragma("unroll") for (int i = 0; i < 4; ++i) {                          \
        int row = wr * 64 + i * 16 + l15;                                      \
        af[i] = *(const bf16x8*)&As[row * 64 + ((rb ^ (row & 7)) << 3)];       \
      }                                                                        \
      _Pragma("unroll") for (int j = 0; j < 4; ++j) {                          \
        int col = wc * 64 + j * 16 + l15;                                      \
        bg[j] = *(const bf16x8*)&Bs[col * 64 + ((rb ^ (col & 7)) << 3)];       \
      }                                                                        \
      _Pragma("unroll") for (int i = 0; i < 4; ++i)                            \
        _Pragma("unroll") for (int j = 0; j < 4; ++j)                          \
          acc[i][j] =                                                          \
              __builtin_amdgcn_mfma_f32_16x16x32_bf16(af[i], bg[j], acc[i][j], \
                                                      0, 0, 0);                \
    }                                                                          \
  }

  STAGE_G(0, 0);
  __syncthreads();  // drains vmcnt(0): buf0 ready
  for (int ks = 0; ks < 23; ++ks) {
    STAGE_G(ks + 1, (ks + 1) & 1);  // next tile in flight under compute
    COMPUTE_G(ks & 1);
    __syncthreads();  // drains vmcnt(0): next buf ready; cur buf reusable
  }
  COMPUTE_G(1);  // ks = 23

#undef STAGE_G
#undef COMPUTE_G

  if (EPI == 0) {
#pragma unroll
    for (int j = 0; j < 4; ++j) {
      int col = bx * 128 + wc * 64 + j * 16 + l15;
      float bj = bias ? bias[col] : 0.f;
#pragma unroll
      for (int i = 0; i < 4; ++i) {
        int row0 = by * 128 + wr * 64 + i * 16 + g * 4;
#pragma unroll
        for (int r = 0; r < 4; ++r)
          C[(size_t)(row0 + r) * N + col] = acc[i][j][r] + bj;
      }
    }
  } else {
    // stage hi -> lds[0..16383], lo -> lds[16384..32767] as [128 r][128 c]
    __syncthreads();  // all waves done reading K-buffers
#pragma unroll
    for (int j = 0; j < 4; ++j) {
      int cl = wc * 64 + j * 16 + l15;
      float bj = bias[bx * 128 + cl];
#pragma unroll
      for (int i = 0; i < 4; ++i) {
        int rl0 = wr * 64 + i * 16 + g * 4;
#pragma unroll
        for (int r = 0; r < 4; ++r) {
          float v = (acc[i][j][r] + bj) * 0.125f;
          ushort h = f2bf(v), lo = f2bf(v - bf2f(h));
          lds[(rl0 + r) * 128 + cl] = h;
          lds[16384 + (rl0 + r) * 128 + cl] = lo;
        }
      }
    }
    __syncthreads();
    // coalesced copy: chunk c -> row r=c>>4, ck=c&15; head=bx*2+(ck>>3)
#pragma unroll
    for (int it = 0; it < 8; ++it) {
      int c = tid + it * 256;
      int r = c >> 4, ck = c & 15;
      int grow = by * 128 + r;
      size_t base = ((size_t)grow * 8 + bx * 2 + (ck >> 3)) * 128 + (ck & 7) * 8;
      *(uint4*)(Qs + base) = *(const uint4*)&lds[r * 128 + ck * 8];
      *(uint4*)(Qs + base + 64) = *(const uint4*)&lds[16384 + r * 128 + ck * 8];
    }
  }
}

// fused q-proj (512 work-ids) + kv-proj (64 work-ids), XCD-swizzled
__global__ __launch_bounds__(256) void proj_fused_kernel(
    const ushort* __restrict__ xq, const ushort* __restrict__ Wq_,
    const float* __restrict__ bq, ushort* __restrict__ Qs,
    const ushort* __restrict__ xkv_, const ushort* __restrict__ Wkv_,
    const float* __restrict__ bkv, float* __restrict__ kvb) {
  __shared__ __align__(16) ushort lds[32768];
  int bid = xcd_swz(blockIdx.x, 576);
  if (bid < 512)
    gemm_body<1>(xq, Wq_, bq, nullptr, Qs, 512, bid & 3, bid >> 2, lds);
  else {
    int b2 = bid - 512;
    gemm_body<0>(xkv_, Wkv_, bkv, kvb, nullptr, 1024, b2 & 7, b2 >> 3, lds);
  }
}

// out-proj, XCD-swizzled
__global__ __launch_bounds__(256) void gemm_out_kernel(
    const ushort* __restrict__ A, const ushort* __restrict__ Bw,
    const float* __restrict__ bias, float* __restrict__ C) {
  __shared__ __align__(16) ushort lds[32768];
  int bid = xcd_swz(blockIdx.x, 512);
  gemm_body<0>(A, Bw, bias, C, nullptr, 512, bid & 3, bid >> 2, lds);
}

// ---------------- conv as split-16 MFMA GEMM, double-buffered ----------------
__global__ __launch_bounds__(256) void conv_mfma_kernel(
    const ushort* __restrict__ xq, const ushort* __restrict__ Wsr_,
    float* __restrict__ part) {
  __shared__ __align__(16) ushort lds[32768];
  int bid = xcd_swz(blockIdx.x, 512);
  int bx = bid & 3, by = (bid >> 2) & 7, z = bid >> 5;
  int kh = z >> 2, kw = z & 3;
  int tid = threadIdx.x;
  int lane = tid & 63, w = tid >> 6;
  int wr = w >> 1, wc = w & 1;
  int l15 = lane & 15, g = lane >> 4;
  int srow = lane >> 3;
  int scol = (lane & 7) ^ srow;

  const ushort* aBase[4];
#pragma unroll
  for (int t = 0; t < 4; ++t) {
    int gm = by * 128 + w * 32 + t * 8 + srow;
    int xr = (gm >> 8) * 4096 + ((((gm >> 4) & 15) << 2) + kh) * 64 +
             ((gm & 15) << 2) + kw;
    aBase[t] = xq + (size_t)xr * 1024 + scol * 8;
  }
  const ushort* bBase =
      Wsr_ + ((size_t)z * 512 + bx * 128 + w * 32 + srow) * 1024 + scol * 8;

  f32x4 acc[4][4];
#pragma unroll
  for (int i = 0; i < 4; ++i)
#pragma unroll
    for (int j = 0; j < 4; ++j) acc[i][j] = (f32x4){0.f, 0.f, 0.f, 0.f};

#define STAGE_C(ks, buf)                                              \
  {                                                                   \
    int kk = (ks) * 64;                                               \
    int ap = kk - (kk >= 1024 ? 1024 : 0);                            \
    int bp = kk - (kk >= 512 ? 512 : 0);                              \
    ushort* aD = lds + (buf) * 16384 + w * 2048;                      \
    ushort* bD = lds + (buf) * 16384 + 8192 + w * 2048;               \
    _Pragma("unroll") for (int t = 0; t < 4; ++t) {                   \
      gload16(aBase[t] + ap, aD + t * 512);                           \
      gload16(bBase + (size_t)t * 8192 + bp, bD + t * 512);           \
    }                                                                 \
  }

#define COMPUTE_C(buf)                                                         \
  {                                                                            \
    const ushort* As = lds + (buf) * 16384;                                    \
    const ushort* Bs = As + 8192;                                              \
    _Pragma("unroll") for (int kk2 = 0; kk2 < 2; ++kk2) {                      \
      int rb = kk2 * 4 + g;                                                    \
      bf16x8 af[4], bg[4];                                                     \
      _Pragma("unroll") for (int i = 0; i < 4; ++i) {                          \
        int row = wr * 64 + i * 16 + l15;                                      \
        af[i] = *(const bf16x8*)&As[row * 64 + ((rb ^ (row & 7)) << 3)];       \
      }                                                                        \
      _Pragma("unroll") for (int j = 0; j < 4; ++j) {                          \
        int col = wc * 64 + j * 16 + l15;                                      \
        bg[j] = *(const bf16x8*)&Bs[col * 64 + ((rb ^ (col & 7)) << 3)];       \
      }                                                                        \
      _Pragma("unroll") for (int i = 0; i < 4; ++i)                            \
        _Pragma("unroll") for (int j = 0; j < 4; ++j)                          \
          acc[i][j] =                                                          \
              __builtin_amdgcn_mfma_f32_16x16x32_bf16(af[i], bg[j], acc[i][j], \
                                                      0, 0, 0);                \
    }                                                                          \
  }

  STAGE_C(0, 0);
  __syncthreads();
  for (int ks = 0; ks < 23; ++ks) {
    STAGE_C(ks + 1, (ks + 1) & 1);
    COMPUTE_C(ks & 1);
    __syncthreads();
  }
  COMPUTE_C(1);

#undef STAGE_C
#undef COMPUTE_C

  float* Cp = part + (size_t)z * 524288;
#pragma unroll
  for (int j = 0; j < 4; ++j) {
    int col = bx * 128 + wc * 64 + j * 16 + l15;
#pragma unroll
    for (int i = 0; i < 4; ++i) {
      int row0 = by * 128 + wr * 64 + i * 16 + g * 4;
#pragma unroll
      for (int r = 0; r < 4; ++r)
        Cp[(size_t)(row0 + r) * 512 + col] = acc[i][j][r];
    }
  }
}

// ---------------- partial-sum(16) + bias + LayerNorm -> split-bf16 ----------------
__global__ __launch_bounds__(256) void ln_kernel(
    const float* __restrict__ part, const float* __restrict__ bsr,
    const float* __restrict__ gamma, const float* __restrict__ beta,
    ushort* __restrict__ xkv_) {
  int row = blockIdx.x;
  int t = threadIdx.x;
  float v0 = bsr[t], v1 = bsr[t + 256];
  for (int p = 0; p < 16; ++p) {
    v0 += part[(size_t)p * 524288 + (size_t)row * 512 + t];
    v1 += part[(size_t)p * 524288 + (size_t)row * 512 + t + 256];
  }
  float s = v0 + v1, sq = v0 * v0 + v1 * v1;
#pragma unroll
  for (int o = 1; o < 64; o <<= 1) {
    s += __shfl_xor(s, o);
    sq += __shfl_xor(sq, o);
  }
  __shared__ float red[8];
  int wv = t >> 6;
  if ((t & 63) == 0) { red[wv] = s; red[4 + wv] = sq; }
  __syncthreads();
  s = red[0] + red[1] + red[2] + red[3];
  sq = red[4] + red[5] + red[6] + red[7];
  float mu = s * (1.0f / 512.0f);
  float var = sq * (1.0f / 512.0f) - mu * mu;
  float rs = rsqrtf(var + 1e-5f);
  float y0 = (v0 - mu) * rs * gamma[t] + beta[t];
  float y1 = (v1 - mu) * rs * gamma[t + 256] + beta[t + 256];
  ushort h0 = f2bf(y0), h1 = f2bf(y1);
  xkv_[(size_t)row * 1024 + t] = h0;
  xkv_[(size_t)row * 1024 + t + 256] = h1;
  xkv_[(size_t)row * 1024 + 512 + t] = f2bf(y0 - bf2f(h0));
  xkv_[(size_t)row * 1024 + 512 + t + 256] = f2bf(y1 - bf2f(h1));
}

// ---------------- kv prep: kvb fp32 -> Kq split [bh][256][128], Vt split [bh][64][512]
__global__ __launch_bounds__(256) void kvprep_kernel(
    const float* __restrict__ kvb, ushort* __restrict__ Kq,
    ushort* __restrict__ Vt) {
  int gid = blockIdx.x * 256 + threadIdx.x;  // 131072
  int row = gid >> 7, c8 = (gid & 127) << 3;
  int b = row >> 8, kk = row & 255;
  float4 a = *(const float4*)(kvb + (size_t)row * 1024 + c8);
  float4 bb = *(const float4*)(kvb + (size_t)row * 1024 + c8 + 4);
  float vv[8] = {a.x, a.y, a.z, a.w, bb.x, bb.y, bb.z, bb.w};
  ushort h[8], l[8];
#pragma unroll
  for (int e = 0; e < 8; ++e) { h[e] = f2bf(vv[e]); l[e] = f2bf(vv[e] - bf2f(h[e])); }
  if (c8 < 512) {
    int hh = c8 >> 6, d = c8 & 63;
    uint4 hp, lp;
    hp.x = h[0] | ((uint)h[1] << 16); hp.y = h[2] | ((uint)h[3] << 16);
    hp.z = h[4] | ((uint)h[5] << 16); hp.w = h[6] | ((uint)h[7] << 16);
    lp.x = l[0] | ((uint)l[1] << 16); lp.y = l[2] | ((uint)l[3] << 16);
    lp.z = l[4] | ((uint)l[5] << 16); lp.w = l[6] | ((uint)l[7] << 16);
    size_t base = ((size_t)((b * 8 + hh) * 256) + kk) * 128 + d;
    *(uint4*)(Kq + base) = hp;
    *(uint4*)(Kq + base + 64) = lp;
  } else {
    int c = c8 - 512;
    int hh = c >> 6, d0 = c & 63;
#pragma unroll
    for (int jj = 0; jj < 8; ++jj) {
      size_t base = ((size_t)((b * 8 + hh) * 64) + d0 + jj) * 512 + kk;
      Vt[base] = h[jj];
      Vt[base + 256] = l[jj];
    }
  }
}

// ---------------- MFMA flash attention ----------------
__global__ __launch_bounds__(256) void attn_kernel(
    const ushort* __restrict__ Qs, const ushort* __restrict__ Kq,
    const ushort* __restrict__ Vt, ushort* __restrict__ attno) {
  __shared__ __align__(16) char arena[16384 + 16384 + 8192];
  ushort* KsL = (ushort*)arena;            // [64 kk][128: hi|lo], swizzled
  ushort* VtL = (ushort*)(arena + 16384);  // [64 d][128: hi|lo kk], swizzled
  ushort* PL = (ushort*)(arena + 32768);   // [64 q][64 kk] bf16, swizzled
  float* ob = (float*)arena;               // [64 d][68 q] epilogue alias

  int tid = threadIdx.x;
  int qb = blockIdx.x, h = blockIdx.y, b = blockIdx.z;
  int n0 = qb * 64, bh = b * 8 + h;
  int lane = tid & 63, w = tid >> 6;
  int q15 = lane & 15, g = lane >> 4;
  int qrow = w * 16 + q15;

  const ushort* qptr = Qs + ((size_t)(b * 4096 + n0 + qrow) * 8 + h) * 128;
  bf16x8 qf[2][2];
#pragma unroll
  for (int s = 0; s < 2; ++s)
#pragma unroll
    for (int kb = 0; kb < 2; ++kb)
      qf[s][kb] = *(const bf16x8*)(qptr + s * 64 + kb * 32 + g * 8);

  f32x4 accO[4];
#pragma unroll
  for (int t = 0; t < 4; ++t) accO[t] = (f32x4){0.f, 0.f, 0.f, 0.f};
  float m = -1e30f, l = 0.f;

  const ushort* kbase = Kq + (size_t)bh * 256 * 128;
  const ushort* vbase = Vt + (size_t)bh * 64 * 512;

  for (int c = 0; c < 4; ++c) {
    __syncthreads();
#pragma unroll
    for (int i = 0; i < 4; ++i) {
      int idx = tid + i * 256;
      int r = idx >> 4, blk = idx & 15;
      uint4 kv4 = *(const uint4*)(kbase + (size_t)(c * 64 + r) * 128 + blk * 8);
      *(uint4*)&KsL[r * 128 + ((blk ^ (r & 7)) << 3)] = kv4;
      uint4 vv4 = *(const uint4*)(vbase + (size_t)r * 512 + ((blk >> 3) << 8) +
                                  c * 64 + ((blk & 7) << 3));
      *(uint4*)&VtL[r * 128 + ((blk ^ (r & 7)) << 3)] = vv4;
    }
    __syncthreads();

    f32x4 accS[4];
#pragma unroll
    for (int t = 0; t < 4; ++t) accS[t] = (f32x4){0.f, 0.f, 0.f, 0.f};
#pragma unroll
    for (int kb = 0; kb < 2; ++kb) {
      bf16x8 ak[4];
#pragma unroll
      for (int t = 0; t < 4; ++t) {
        int kkr = t * 16 + q15;
        ak[t] = *(const bf16x8*)&KsL[kkr * 128 + (((kb * 4 + g) ^ (kkr & 7)) << 3)];
      }
#pragma unroll
      for (int t = 0; t < 4; ++t)
        accS[t] = __builtin_amdgcn_mfma_f32_16x16x32_bf16(ak[t], qf[0][kb], accS[t], 0, 0, 0);
#pragma unroll
      for (int t = 0; t < 4; ++t)
        accS[t] = __builtin_amdgcn_mfma_f32_16x16x32_bf16(ak[t], qf[1][kb], accS[t], 0, 0, 0);
#pragma unroll
      for (int t = 0; t < 4; ++t) {
        int kkr = t * 16 + q15;
        bf16x8 al = *(const bf16x8*)&KsL[kkr * 128 + (((8 + kb * 4 + g) ^ (kkr & 7)) << 3)];
        accS[t] = __builtin_amdgcn_mfma_f32_16x16x32_bf16(al, qf[0][kb], accS[t], 0, 0, 0);
      }
    }

    float mx = -1e30f;
#pragma unroll
    for (int t = 0; t < 4; ++t)
#pragma unroll
      for (int r = 0; r < 4; ++r) mx = fmaxf(mx, accS[t][r]);
    mx = fmaxf(mx, __shfl_xor(mx, 16));
    mx = fmaxf(mx, __shfl_xor(mx, 32));
    float mn = fmaxf(m, mx);
    float fac = __expf(m - mn);
    m = mn;
    float sum = 0.f;
    ushort ph[4][4];
#pragma unroll
    for (int t = 0; t < 4; ++t)
#pragma unroll
      for (int r = 0; r < 4; ++r) {
        float p = __expf(accS[t][r] - mn);
        ushort hp = f2bf(p);
        ph[t][r] = hp;
        sum += bf2f(hp);
      }
    sum += __shfl_xor(sum, 16);
    sum += __shfl_xor(sum, 32);
    l = l * fac + sum;
#pragma unroll
    for (int t = 0; t < 4; ++t) {
      accO[t][0] *= fac; accO[t][1] *= fac; accO[t][2] *= fac; accO[t][3] *= fac;
    }
#pragma unroll
    for (int t = 0; t < 4; ++t)
#pragma unroll
      for (int rp = 0; rp < 4; rp += 2) {
        uint u = ph[t][rp] | ((uint)ph[t][rp + 1] << 16);
        int kkl = t * 16 + g * 4 + rp;
        int blk = kkl >> 3, off = kkl & 7;
        *(uint*)((char*)PL + qrow * 128 + ((blk ^ (q15 & 7)) << 4) + off * 2) = u;
      }
    __syncthreads();

    bf16x8 pf[2];
#pragma unroll
    for (int kb = 0; kb < 2; ++kb)
      pf[kb] = *(const bf16x8*)((char*)PL + qrow * 128 + (((kb * 4 + g) ^ (q15 & 7)) << 4));
#pragma unroll
    for (int s = 0; s < 2; ++s)
#pragma unroll
      for (int kb = 0; kb < 2; ++kb)
#pragma unroll
        for (int t = 0; t < 4; ++t) {
          int d = t * 16 + q15;
          bf16x8 vf =
              *(const bf16x8*)&VtL[d * 128 + (((s * 8 + kb * 4 + g) ^ (d & 7)) << 3)];
          accO[t] = __builtin_amdgcn_mfma_f32_16x16x32_bf16(vf, pf[kb], accO[t], 0, 0, 0);
        }
  }

  float inv = 1.0f / l;
  __syncthreads();
#pragma unroll
  for (int t = 0; t < 4; ++t)
#pragma unroll
    for (int r = 0; r < 4; ++r)
      ob[(t * 16 + g * 4 + r) * 68 + qrow] = accO[t][r] * inv;
  __syncthreads();
#pragma unroll
  for (int i = 0; i < 2; ++i) {
    int idx = tid + i * 256;
    int qq = idx >> 3, d8 = (idx & 7) << 3;
    ushort hh[8], ll[8];
#pragma unroll
    for (int jj = 0; jj < 8; ++jj) {
      float v = ob[(d8 + jj) * 68 + qq];
      hh[jj] = f2bf(v);
      ll[jj] = f2bf(v - bf2f(hh[jj]));
    }
    uint4 hp, lp;
    hp.x = hh[0] | ((uint)hh[1] << 16); hp.y = hh[2] | ((uint)hh[3] << 16);
    hp.z = hh[4] | ((uint)hh[5] << 16); hp.w = hh[6] | ((uint)hh[7] << 16);
    lp.x = ll[0] | ((uint)ll[1] << 16); lp.y = ll[2] | ((uint)ll[3] << 16);
    lp.z = ll[4] | ((uint)ll[5] << 16); lp.w = ll[6] | ((uint)ll[7] << 16);
    size_t rowb = (size_t)(b * 4096 + n0 + qq) * 1024 + h * 64 + d8;
    *(uint4*)(attno + rowb) = hp;
    *(uint4*)(attno + rowb + 512) = lp;
  }
}

// ---------------- launch ----------------
extern "C" void kernel_launch(void* const* d_in, const int* in_sizes, int n_in,
                              void* d_out, int out_size, void* d_ws, size_t ws_size,
                              hipStream_t stream) {
  const float* x     = (const float*)d_in[0];
  const float* Wq    = (const float*)d_in[1];
  const float* bq    = (const float*)d_in[2];
  const float* Wk    = (const float*)d_in[3];
  const float* bk    = (const float*)d_in[4];
  const float* Wv    = (const float*)d_in[5];
  const float* bv    = (const float*)d_in[6];
  const float* Wp    = (const float*)d_in[7];
  const float* bp    = (const float*)d_in[8];
  const float* Wsr   = (const float*)d_in[9];
  const float* bsr   = (const float*)d_in[10];
  const float* gamma = (const float*)d_in[11];
  const float* beta  = (const float*)d_in[12];

  float* ws = (float*)d_ws;
  // regionA (8,388,608 fl): xq (dies after proj launch); then attno_
  ushort* xq     = (ushort*)ws;
  ushort* attno_ = (ushort*)ws;
  // regionB (8,388,608 fl): conv_part [16][1024][512] f32; then Qsplit
  float*  conv_part = ws + 8388608;
  ushort* Qsplit    = (ushort*)(ws + 8388608);
  // tail regions
  ushort* Wsr_ = (ushort*)(ws + 16777216);  // 8,388,608 us = 4,194,304 fl
  float*  kvb  = ws + 20971520;             // 1,048,576 fl
  ushort* Kq   = (ushort*)(ws + 22020096);  // 1,048,576 us
  ushort* Vt   = (ushort*)(ws + 22544384);  // 1,048,576 us
  ushort* Wq_  = (ushort*)(ws + 23068672);
  ushort* Wp_  = (ushort*)(ws + 23330816);
  ushort* Wkv_ = (ushort*)(ws + 23592960);
  ushort* xkv_ = (ushort*)(ws + 24117248);
  float*  bkv  = ws + 24641536;
  float* outp = (float*)d_out;

  prep_kernel<<<8705, 256, 0, stream>>>(x, Wq, Wp, Wk, Wv, Wsr, bk, bv,
                                        xq, Wq_, Wp_, Wkv_, Wsr_, bkv);
  conv_mfma_kernel<<<512, 256, 0, stream>>>(xq, Wsr_, conv_part);
  ln_kernel<<<1024, 256, 0, stream>>>(conv_part, bsr, gamma, beta, xkv_);
  proj_fused_kernel<<<576, 256, 0, stream>>>(xq, Wq_, bq, Qsplit, xkv_, Wkv_, bkv, kvb);
  kvprep_kernel<<<512, 256, 0, stream>>>(kvb, Kq, Vt);
  attn_kernel<<<dim3(64, 8, 4), 256, 0, stream>>>(Qsplit, Kq, Vt, attno_);
  gemm_out_kernel<<<512, 256, 0, stream>>>(attno_, Wp_, bp, outp);
}

// Round 8
// 178.375 us; speedup vs baseline: 1.2046x; 1.0416x over previous
//
#include <hip/hip_runtime.h>

// B=4, H=W=64, N=4096, C=512, HEAD=8, dh=64, SR=4, Nk=256
// Split-bf16: val = hi + lo (both bf16). 3-term product drops only lo*lo (~4e-6 rel).

typedef __bf16 bf16x8 __attribute__((ext_vector_type(8)));
typedef float f32x4 __attribute__((ext_vector_type(4)));

__device__ __forceinline__ ushort f2bf(float v) {
  uint u = __float_as_uint(v);
  return (ushort)((u + 0x7FFFu + ((u >> 16) & 1u)) >> 16);
}
__device__ __forceinline__ float bf2f(ushort h) {
  return __uint_as_float((uint)h << 16);
}
__device__ __forceinline__ void gload16(const void* g, void* l) {
  __builtin_amdgcn_global_load_lds(
      (const __attribute__((address_space(1))) void*)g,
      (__attribute__((address_space(3))) void*)l, 16, 0, 0);
}
// bijective XCD swizzle for nwg % 8 == 0: work-ids contiguous per XCD
__device__ __forceinline__ int xcd_swz(int bid, int nwg) {
  int cpx = nwg >> 3;
  return (bid & 7) * cpx + (bid >> 3);
}

// ---------------- fused prep: convert x, W's, Wsr, biases ----------------
__global__ __launch_bounds__(256) void prep_kernel(
    const float* __restrict__ x, const float* __restrict__ Wq,
    const float* __restrict__ Wp, const float* __restrict__ Wk,
    const float* __restrict__ Wv, const float* __restrict__ Wsr,
    const float* __restrict__ bk, const float* __restrict__ bv,
    ushort* __restrict__ xq, ushort* __restrict__ Wq_,
    ushort* __restrict__ Wp_, ushort* __restrict__ Wkv_,
    ushort* __restrict__ Wsr_, float* __restrict__ bkv) {
  __shared__ float t[32][33];
  int bid = blockIdx.x, tid = threadIdx.x;
  if (bid < 4096 + 512) {
    const float* src;
    ushort* dst;
    int gid;
    if (bid < 4096) {  // x -> x' split
      src = x; dst = xq; gid = bid * 256 + tid;
    } else {
      int z = (bid - 4096) >> 7;
      src = (z == 0) ? Wq : (z == 1) ? Wp : (z == 2) ? Wk : Wv;
      dst = (z == 0) ? Wq_ : (z == 1) ? Wp_ : (z == 2) ? Wkv_ : (Wkv_ + 512 * 1024);
      gid = ((bid - 4096) & 127) * 256 + tid;
    }
    int row = gid >> 6, c8 = (gid & 63) << 3;
    float4 a = *(const float4*)(src + (size_t)row * 512 + c8);
    float4 b = *(const float4*)(src + (size_t)row * 512 + c8 + 4);
    ushort h[8], l[8];
    float vv[8] = {a.x, a.y, a.z, a.w, b.x, b.y, b.z, b.w};
#pragma unroll
    for (int e = 0; e < 8; ++e) { h[e] = f2bf(vv[e]); l[e] = f2bf(vv[e] - bf2f(h[e])); }
    uint4 hp, lp;
    hp.x = h[0] | ((uint)h[1] << 16); hp.y = h[2] | ((uint)h[3] << 16);
    hp.z = h[4] | ((uint)h[5] << 16); hp.w = h[6] | ((uint)h[7] << 16);
    lp.x = l[0] | ((uint)l[1] << 16); lp.y = l[2] | ((uint)l[3] << 16);
    lp.z = l[4] | ((uint)l[5] << 16); lp.w = l[6] | ((uint)l[7] << 16);
    *(uint4*)(dst + (size_t)row * 1024 + c8) = hp;
    *(uint4*)(dst + (size_t)row * 1024 + 512 + c8) = lp;
  } else if (bid < 4096 + 512 + 4096) {  // Wsr transpose+split
    int tb = bid - 4608;
    int z = tb >> 8, rem = tb & 255;
    int ci0 = (rem >> 4) << 5, co0 = (rem & 15) << 5;
    int tx = tid & 31, ty = tid >> 5;
#pragma unroll
    for (int i = 0; i < 32; i += 8)
      t[ty + i][tx] = Wsr[((size_t)z * 512 + ci0 + ty + i) * 512 + co0 + tx];
    __syncthreads();
#pragma unroll
    for (int i = 0; i < 32; i += 8) {
      float v = t[tx][ty + i];
      int co = co0 + ty + i, ci = ci0 + tx;
      ushort h = f2bf(v), l = f2bf(v - bf2f(h));
      Wsr_[((size_t)z * 512 + co) * 1024 + ci] = h;
      Wsr_[((size_t)z * 512 + co) * 1024 + 512 + ci] = l;
    }
  } else {  // bias concat
    bkv[tid] = bk[tid]; bkv[tid + 256] = bk[tid + 256];
    bkv[tid + 512] = bv[tid]; bkv[tid + 768] = bv[tid + 256];
  }
}

// ---------------- MFMA GEMM body: double-buffered 2-phase K-loop ----------------
template <int EPI>
__device__ __forceinline__ void gemm_body(
    const ushort* __restrict__ A, const ushort* __restrict__ Bw,
    const float* __restrict__ bias, float* __restrict__ C,
    ushort* __restrict__ Qs, int N, int bx, int by, ushort* lds) {
  int tid = threadIdx.x;
  int lane = tid & 63, w = tid >> 6;
  int wr = w >> 1, wc = w & 1;
  int l15 = lane & 15, g = lane >> 4;
  int srow = lane >> 3;
  int scol = (lane & 7) ^ srow;  // pre-swizzled source block

  const ushort* aBase = A + (size_t)(by * 128 + w * 32 + srow) * 1024 + scol * 8;
  const ushort* bBase = Bw + (size_t)(bx * 128 + w * 32 + srow) * 1024 + scol * 8;

  f32x4 acc[4][4];
#pragma unroll
  for (int i = 0; i < 4; ++i)
#pragma unroll
    for (int j = 0; j < 4; ++j) acc[i][j] = (f32x4){0.f, 0.f, 0.f, 0.f};

#define STAGE_G(ks, buf)                                              \
  {                                                                   \
    int kk = (ks) * 64;                                               \
    int ap = kk - (kk >= 1024 ? 1024 : 0);                            \
    int bp = kk - (kk >= 512 ? 512 : 0);                              \
    ushort* aD = lds + (buf) * 16384 + w * 2048;                      \
    ushort* bD = lds + (buf) * 16384 + 8192 + w * 2048;               \
    _Pragma("unroll") for (int t = 0; t < 4; ++t) {                   \
      gload16(aBase + (size_t)t * 8192 + ap, aD + t * 512);           \
      gload16(bBase + (size_t)t * 8192 + bp, bD + t * 512);           \
    }                                                                 \
  }

#define COMPUTE_G(buf)                                                         \
  {                                                                            \
    const ushort* As = lds + (buf) * 16384;                                    \
    const ushort* Bs = As + 8192;                                              \
    _Pragma("unroll") for (int kk2 = 0; kk2 < 2; ++kk2) {                      \
      int rb = kk2 * 4 + g;                                                    \
      bf16x8 af[4], bg[4];                                                     \
      _Pragma("unroll") for (int i = 0; i < 4; ++i) {                          \
        int row = wr * 64 + i * 16 + l15;                                      \
        af[i] = *(const bf16x8*)&As[row * 64 + ((rb ^ (row & 7)) << 3)];       \
      }                                                                        \
      _Pragma("unroll") for (int j = 0; j < 4; ++j) {                          \
        int col = wc * 64 + j * 16 + l15;                                      \
        bg[j] = *(const bf16x8*)&Bs[col * 64 + ((rb ^ (col & 7)) << 3)];       \
      }                                                                        \
      _Pragma("unroll") for (int i = 0; i < 4; ++i)                            \
        _Pragma("unroll") for (int j = 0; j < 4; ++j)                          \
          acc[i][j] =                                                          \
              __builtin_amdgcn_mfma_f32_16x16x32_bf16(af[i], bg[j], acc[i][j], \
                                                      0, 0, 0);                \
    }                                                                          \
  }

  STAGE_G(0, 0);
  __syncthreads();
  for (int ks = 0; ks < 23; ++ks) {
    STAGE_G(ks + 1, (ks + 1) & 1);
    COMPUTE_G(ks & 1);
    __syncthreads();
  }
  COMPUTE_G(1);

#undef STAGE_G
#undef COMPUTE_G

  if (EPI == 0) {
#pragma unroll
    for (int j = 0; j < 4; ++j) {
      int col = bx * 128 + wc * 64 + j * 16 + l15;
      float bj = bias ? bias[col] : 0.f;
#pragma unroll
      for (int i = 0; i < 4; ++i) {
        int row0 = by * 128 + wr * 64 + i * 16 + g * 4;
#pragma unroll
        for (int r = 0; r < 4; ++r)
          C[(size_t)(row0 + r) * N + col] = acc[i][j][r] + bj;
      }
    }
  } else {
    __syncthreads();
#pragma unroll
    for (int j = 0; j < 4; ++j) {
      int cl = wc * 64 + j * 16 + l15;
      float bj = bias[bx * 128 + cl];
#pragma unroll
      for (int i = 0; i < 4; ++i) {
        int rl0 = wr * 64 + i * 16 + g * 4;
#pragma unroll
        for (int r = 0; r < 4; ++r) {
          float v = (acc[i][j][r] + bj) * 0.125f;
          ushort h = f2bf(v), lo = f2bf(v - bf2f(h));
          lds[(rl0 + r) * 128 + cl] = h;
          lds[16384 + (rl0 + r) * 128 + cl] = lo;
        }
      }
    }
    __syncthreads();
#pragma unroll
    for (int it = 0; it < 8; ++it) {
      int c = tid + it * 256;
      int r = c >> 4, ck = c & 15;
      int grow = by * 128 + r;
      size_t base = ((size_t)grow * 8 + bx * 2 + (ck >> 3)) * 128 + (ck & 7) * 8;
      *(uint4*)(Qs + base) = *(const uint4*)&lds[r * 128 + ck * 8];
      *(uint4*)(Qs + base + 64) = *(const uint4*)&lds[16384 + r * 128 + ck * 8];
    }
  }
}

__global__ __launch_bounds__(256) void proj_fused_kernel(
    const ushort* __restrict__ xq, const ushort* __restrict__ Wq_,
    const float* __restrict__ bq, ushort* __restrict__ Qs,
    const ushort* __restrict__ xkv_, const ushort* __restrict__ Wkv_,
    const float* __restrict__ bkv, float* __restrict__ kvb) {
  __shared__ __align__(16) ushort lds[32768];
  int bid = xcd_swz(blockIdx.x, 576);
  if (bid < 512)
    gemm_body<1>(xq, Wq_, bq, nullptr, Qs, 512, bid & 3, bid >> 2, lds);
  else {
    int b2 = bid - 512;
    gemm_body<0>(xkv_, Wkv_, bkv, kvb, nullptr, 1024, b2 & 7, b2 >> 3, lds);
  }
}

__global__ __launch_bounds__(256) void gemm_out_kernel(
    const ushort* __restrict__ A, const ushort* __restrict__ Bw,
    const float* __restrict__ bias, float* __restrict__ C) {
  __shared__ __align__(16) ushort lds[32768];
  int bid = xcd_swz(blockIdx.x, 512);
  gemm_body<0>(A, Bw, bias, C, nullptr, 512, bid & 3, bid >> 2, lds);
}

// ---------------- conv as split-16 MFMA GEMM, double-buffered ----------------
__global__ __launch_bounds__(256) void conv_mfma_kernel(
    const ushort* __restrict__ xq, const ushort* __restrict__ Wsr_,
    float* __restrict__ part) {
  __shared__ __align__(16) ushort lds[32768];
  int bid = xcd_swz(blockIdx.x, 512);
  int bx = bid & 3, by = (bid >> 2) & 7, z = bid >> 5;
  int kh = z >> 2, kw = z & 3;
  int tid = threadIdx.x;
  int lane = tid & 63, w = tid >> 6;
  int wr = w >> 1, wc = w & 1;
  int l15 = lane & 15, g = lane >> 4;
  int srow = lane >> 3;
  int scol = (lane & 7) ^ srow;

  const ushort* aBase[4];
#pragma unroll
  for (int t = 0; t < 4; ++t) {
    int gm = by * 128 + w * 32 + t * 8 + srow;
    int xr = (gm >> 8) * 4096 + ((((gm >> 4) & 15) << 2) + kh) * 64 +
             ((gm & 15) << 2) + kw;
    aBase[t] = xq + (size_t)xr * 1024 + scol * 8;
  }
  const ushort* bBase =
      Wsr_ + ((size_t)z * 512 + bx * 128 + w * 32 + srow) * 1024 + scol * 8;

  f32x4 acc[4][4];
#pragma unroll
  for (int i = 0; i < 4; ++i)
#pragma unroll
    for (int j = 0; j < 4; ++j) acc[i][j] = (f32x4){0.f, 0.f, 0.f, 0.f};

#define STAGE_C(ks, buf)                                              \
  {                                                                   \
    int kk = (ks) * 64;                                               \
    int ap = kk - (kk >= 1024 ? 1024 : 0);                            \
    int bp = kk - (kk >= 512 ? 512 : 0);                              \
    ushort* aD = lds + (buf) * 16384 + w * 2048;                      \
    ushort* bD = lds + (buf) * 16384 + 8192 + w * 2048;               \
    _Pragma("unroll") for (int t = 0; t < 4; ++t) {                   \
      gload16(aBase[t] + ap, aD + t * 512);                           \
      gload16(bBase + (size_t)t * 8192 + bp, bD + t * 512);           \
    }                                                                 \
  }

#define COMPUTE_C(buf)                                                         \
  {                                                                            \
    const ushort* As = lds + (buf) * 16384;                                    \
    const ushort* Bs = As + 8192;                                              \
    _Pragma("unroll") for (int kk2 = 0; kk2 < 2; ++kk2) {                      \
      int rb = kk2 * 4 + g;                                                    \
      bf16x8 af[4], bg[4];                                                     \
      _Pragma("unroll") for (int i = 0; i < 4; ++i) {                          \
        int row = wr * 64 + i * 16 + l15;                                      \
        af[i] = *(const bf16x8*)&As[row * 64 + ((rb ^ (row & 7)) << 3)];       \
      }                                                                        \
      _Pragma("unroll") for (int j = 0; j < 4; ++j) {                          \
        int col = wc * 64 + j * 16 + l15;                                      \
        bg[j] = *(const bf16x8*)&Bs[col * 64 + ((rb ^ (col & 7)) << 3)];       \
      }                                                                        \
      _Pragma("unroll") for (int i = 0; i < 4; ++i)                            \
        _Pragma("unroll") for (int j = 0; j < 4; ++j)                          \
          acc[i][j] =                                                          \
              __builtin_amdgcn_mfma_f32_16x16x32_bf16(af[i], bg[j], acc[i][j], \
                                                      0, 0, 0);                \
    }                                                                          \
  }

  STAGE_C(0, 0);
  __syncthreads();
  for (int ks = 0; ks < 23; ++ks) {
    STAGE_C(ks + 1, (ks + 1) & 1);
    COMPUTE_C(ks & 1);
    __syncthreads();
  }
  COMPUTE_C(1);

#undef STAGE_C
#undef COMPUTE_C

  float* Cp = part + (size_t)z * 524288;
#pragma unroll
  for (int j = 0; j < 4; ++j) {
    int col = bx * 128 + wc * 64 + j * 16 + l15;
#pragma unroll
    for (int i = 0; i < 4; ++i) {
      int row0 = by * 128 + wr * 64 + i * 16 + g * 4;
#pragma unroll
      for (int r = 0; r < 4; ++r)
        Cp[(size_t)(row0 + r) * 512 + col] = acc[i][j][r];
    }
  }
}

// ---------------- partial-sum(16) + bias + LayerNorm -> split-bf16 ----------------
__global__ __launch_bounds__(256) void ln_kernel(
    const float* __restrict__ part, const float* __restrict__ bsr,
    const float* __restrict__ gamma, const float* __restrict__ beta,
    ushort* __restrict__ xkv_) {
  int row = blockIdx.x;
  int t = threadIdx.x;
  float v0 = bsr[t], v1 = bsr[t + 256];
  for (int p = 0; p < 16; ++p) {
    v0 += part[(size_t)p * 524288 + (size_t)row * 512 + t];
    v1 += part[(size_t)p * 524288 + (size_t)row * 512 + t + 256];
  }
  float s = v0 + v1, sq = v0 * v0 + v1 * v1;
#pragma unroll
  for (int o = 1; o < 64; o <<= 1) {
    s += __shfl_xor(s, o);
    sq += __shfl_xor(sq, o);
  }
  __shared__ float red[8];
  int wv = t >> 6;
  if ((t & 63) == 0) { red[wv] = s; red[4 + wv] = sq; }
  __syncthreads();
  s = red[0] + red[1] + red[2] + red[3];
  sq = red[4] + red[5] + red[6] + red[7];
  float mu = s * (1.0f / 512.0f);
  float var = sq * (1.0f / 512.0f) - mu * mu;
  float rs = rsqrtf(var + 1e-5f);
  float y0 = (v0 - mu) * rs * gamma[t] + beta[t];
  float y1 = (v1 - mu) * rs * gamma[t + 256] + beta[t + 256];
  ushort h0 = f2bf(y0), h1 = f2bf(y1);
  xkv_[(size_t)row * 1024 + t] = h0;
  xkv_[(size_t)row * 1024 + t + 256] = h1;
  xkv_[(size_t)row * 1024 + 512 + t] = f2bf(y0 - bf2f(h0));
  xkv_[(size_t)row * 1024 + 512 + t + 256] = f2bf(y1 - bf2f(h1));
}

// ---------------- kv prep: kvb fp32 -> Kq split [bh][256][128], Vt split [bh][64][512]
__global__ __launch_bounds__(256) void kvprep_kernel(
    const float* __restrict__ kvb, ushort* __restrict__ Kq,
    ushort* __restrict__ Vt) {
  int gid = blockIdx.x * 256 + threadIdx.x;  // 131072
  int row = gid >> 7, c8 = (gid & 127) << 3;
  int b = row >> 8, kk = row & 255;
  float4 a = *(const float4*)(kvb + (size_t)row * 1024 + c8);
  float4 bb = *(const float4*)(kvb + (size_t)row * 1024 + c8 + 4);
  float vv[8] = {a.x, a.y, a.z, a.w, bb.x, bb.y, bb.z, bb.w};
  ushort h[8], l[8];
#pragma unroll
  for (int e = 0; e < 8; ++e) { h[e] = f2bf(vv[e]); l[e] = f2bf(vv[e] - bf2f(h[e])); }
  if (c8 < 512) {
    int hh = c8 >> 6, d = c8 & 63;
    uint4 hp, lp;
    hp.x = h[0] | ((uint)h[1] << 16); hp.y = h[2] | ((uint)h[3] << 16);
    hp.z = h[4] | ((uint)h[5] << 16); hp.w = h[6] | ((uint)h[7] << 16);
    lp.x = l[0] | ((uint)l[1] << 16); lp.y = l[2] | ((uint)l[3] << 16);
    lp.z = l[4] | ((uint)l[5] << 16); lp.w = l[6] | ((uint)l[7] << 16);
    size_t base = ((size_t)((b * 8 + hh) * 256) + kk) * 128 + d;
    *(uint4*)(Kq + base) = hp;
    *(uint4*)(Kq + base + 64) = lp;
  } else {
    int c = c8 - 512;
    int hh = c >> 6, d0 = c & 63;
#pragma unroll
    for (int jj = 0; jj < 8; ++jj) {
      size_t base = ((size_t)((b * 8 + hh) * 64) + d0 + jj) * 512 + kk;
      Vt[base] = h[jj];
      Vt[base + 256] = l[jj];
    }
  }
}

// ---------------- MFMA flash attention v2: 128 q/block, DMA staging, dbuf ----------------
// Block = (qb, h, b): 128 q-rows, 4 waves; wave w owns q rows {w*16+q15, 64+w*16+q15}.
// K/V chunk staged by global_load_lds with pre-swizzled SOURCE (linear LDS dest).
__global__ __launch_bounds__(256, 2) void attn_kernel(
    const ushort* __restrict__ Qs, const ushort* __restrict__ Kq,
    const ushort* __restrict__ Vt, ushort* __restrict__ attno) {
  __shared__ __align__(16) char arena[81920];
  ushort* KsL = (ushort*)arena;            // [2][64 kk][128], swizzled content
  ushort* VtL = (ushort*)(arena + 32768);  // [2][64 d][128], swizzled content
  ushort* PL = (ushort*)(arena + 65536);   // [128 q][64 kk] bf16, swizzled
  float* ob = (float*)arena;               // [64 d][68 q] epilogue alias

  int tid = threadIdx.x;
  int qb = blockIdx.x, h = blockIdx.y, b = blockIdx.z;
  int n0 = qb * 128, bh = b * 8 + h;
  int lane = tid & 63, w = tid >> 6;
  int q15 = lane & 15, g = lane >> 4;

  const ushort* kbase = Kq + (size_t)bh * 256 * 128;
  const ushort* vbase = Vt + (size_t)bh * 64 * 512;

  // Q fragments for both q-sets, held in registers
  bf16x8 qf[2][2][2];  // [set][hi/lo][kb]
#pragma unroll
  for (int set = 0; set < 2; ++set) {
    const ushort* qptr =
        Qs + ((size_t)(b * 4096 + n0 + set * 64 + w * 16 + q15) * 8 + h) * 128;
#pragma unroll
    for (int s = 0; s < 2; ++s)
#pragma unroll
      for (int kb = 0; kb < 2; ++kb)
        qf[set][s][kb] = *(const bf16x8*)(qptr + s * 64 + kb * 32 + g * 8);
  }

  f32x4 accO[2][4];
#pragma unroll
  for (int set = 0; set < 2; ++set)
#pragma unroll
    for (int t = 0; t < 4; ++t) accO[set][t] = (f32x4){0.f, 0.f, 0.f, 0.f};
  float m[2] = {-1e30f, -1e30f}, l[2] = {0.f, 0.f};

  // DMA staging: wave w stages rows w*16..w*16+15 of K and V (4 instrs each,
  // 4 rows per instr). LDS dest linear; global source pre-swizzled so LDS
  // slot (r, s) holds block s^(r&7).
#define STAGE_A(cc, buf)                                                     \
  {                                                                          \
    _Pragma("unroll") for (int i = 0; i < 4; ++i) {                          \
      int rb_ = w * 16 + i * 4;                                              \
      int r_ = rb_ + (lane >> 4);                                            \
      int sb_ = (lane & 15) ^ (r_ & 7);                                      \
      gload16(kbase + (size_t)((cc) * 64 + r_) * 128 + (sb_ << 3),           \
              KsL + (buf) * 8192 + rb_ * 128);                               \
      gload16(vbase + (size_t)r_ * 512 + ((sb_ >> 3) << 8) + (cc) * 64 +     \
                  ((sb_ & 7) << 3),                                          \
              VtL + (buf) * 8192 + rb_ * 128);                               \
    }                                                                        \
  }

  STAGE_A(0, 0);
  __syncthreads();

  for (int c = 0; c < 4; ++c) {
    int buf = c & 1;
    if (c < 3) STAGE_A(c + 1, buf ^ 1);
    const ushort* Ks = KsL + buf * 8192;
    const ushort* Vs = VtL + buf * 8192;

    // S^T = Khi*Qhi + Khi*Qlo + Klo*Qhi, both q-sets share K fragments
    f32x4 accS[2][4];
#pragma unroll
    for (int set = 0; set < 2; ++set)
#pragma unroll
      for (int t = 0; t < 4; ++t) accS[set][t] = (f32x4){0.f, 0.f, 0.f, 0.f};
#pragma unroll
    for (int kb = 0; kb < 2; ++kb) {
      bf16x8 ak[4], al[4];
#pragma unroll
      for (int t = 0; t < 4; ++t) {
        int kkr = t * 16 + q15;
        ak[t] = *(const bf16x8*)&Ks[kkr * 128 + (((kb * 4 + g) ^ (kkr & 7)) << 3)];
        al[t] = *(const bf16x8*)&Ks[kkr * 128 + (((8 + kb * 4 + g) ^ (kkr & 7)) << 3)];
      }
#pragma unroll
      for (int set = 0; set < 2; ++set) {
#pragma unroll
        for (int t = 0; t < 4; ++t)
          accS[set][t] = __builtin_amdgcn_mfma_f32_16x16x32_bf16(
              ak[t], qf[set][0][kb], accS[set][t], 0, 0, 0);
#pragma unroll
        for (int t = 0; t < 4; ++t)
          accS[set][t] = __builtin_amdgcn_mfma_f32_16x16x32_bf16(
              ak[t], qf[set][1][kb], accS[set][t], 0, 0, 0);
#pragma unroll
        for (int t = 0; t < 4; ++t)
          accS[set][t] = __builtin_amdgcn_mfma_f32_16x16x32_bf16(
              al[t], qf[set][0][kb], accS[set][t], 0, 0, 0);
      }
    }

    // online softmax per set; write unnormalized bf16 P to PL
#pragma unroll
    for (int set = 0; set < 2; ++set) {
      int qrowL = set * 64 + w * 16 + q15;
      float mx = -1e30f;
#pragma unroll
      for (int t = 0; t < 4; ++t)
#pragma unroll
        for (int r = 0; r < 4; ++r) mx = fmaxf(mx, accS[set][t][r]);
      mx = fmaxf(mx, __shfl_xor(mx, 16));
      mx = fmaxf(mx, __shfl_xor(mx, 32));
      float mn = fmaxf(m[set], mx);
      float fac = __expf(m[set] - mn);
      m[set] = mn;
      float sum = 0.f;
      ushort ph[4][4];
#pragma unroll
      for (int t = 0; t < 4; ++t)
#pragma unroll
        for (int r = 0; r < 4; ++r) {
          float p = __expf(accS[set][t][r] - mn);
          ushort hp = f2bf(p);
          ph[t][r] = hp;
          sum += bf2f(hp);
        }
      sum += __shfl_xor(sum, 16);
      sum += __shfl_xor(sum, 32);
      l[set] = l[set] * fac + sum;
#pragma unroll
      for (int t = 0; t < 4; ++t) {
        accO[set][t][0] *= fac; accO[set][t][1] *= fac;
        accO[set][t][2] *= fac; accO[set][t][3] *= fac;
      }
#pragma unroll
      for (int t = 0; t < 4; ++t)
#pragma unroll
        for (int rp = 0; rp < 4; rp += 2) {
          uint u = ph[t][rp] | ((uint)ph[t][rp + 1] << 16);
          int kkl = t * 16 + g * 4 + rp;
          int blk = kkl >> 3, off = kkl & 7;
          *(uint*)((char*)PL + qrowL * 128 + ((blk ^ (q15 & 7)) << 4) + off * 2) = u;
        }
    }
    __syncthreads();  // P visible; prefetch drained

    // PV: out^T += Vhi*P^T + Vlo*P^T ; V fragments shared by both sets
    bf16x8 pf[2][2];
#pragma unroll
    for (int set = 0; set < 2; ++set) {
      int qrowL = set * 64 + w * 16 + q15;
#pragma unroll
      for (int kb = 0; kb < 2; ++kb)
        pf[set][kb] = *(const bf16x8*)((char*)PL + qrowL * 128 +
                                       (((kb * 4 + g) ^ (q15 & 7)) << 4));
    }
#pragma unroll
    for (int s = 0; s < 2; ++s)
#pragma unroll
      for (int kb = 0; kb < 2; ++kb)
#pragma unroll
        for (int t = 0; t < 4; ++t) {
          int d = t * 16 + q15;
          bf16x8 vf =
              *(const bf16x8*)&Vs[d * 128 + (((s * 8 + kb * 4 + g) ^ (d & 7)) << 3)];
          accO[0][t] = __builtin_amdgcn_mfma_f32_16x16x32_bf16(vf, pf[0][kb],
                                                               accO[0][t], 0, 0, 0);
          accO[1][t] = __builtin_amdgcn_mfma_f32_16x16x32_bf16(vf, pf[1][kb],
                                                               accO[1][t], 0, 0, 0);
        }
    __syncthreads();  // PL reusable next iter; staging target safe
  }
#undef STAGE_A

  // normalize + transpose via LDS (ob aliases KsL region) + coalesced store
#pragma unroll
  for (int set = 0; set < 2; ++set) {
    if (set) __syncthreads();
    float inv = 1.0f / l[set];
#pragma unroll
    for (int t = 0; t < 4; ++t)
#pragma unroll
      for (int r = 0; r < 4; ++r)
        ob[(t * 16 + g * 4 + r) * 68 + w * 16 + q15] = accO[set][t][r] * inv;
    __syncthreads();
#pragma unroll
    for (int i = 0; i < 2; ++i) {
      int idx = tid + i * 256;
      int qq = idx >> 3, d8 = (idx & 7) << 3;
      ushort hh[8], ll[8];
#pragma unroll
      for (int jj = 0; jj < 8; ++jj) {
        float v = ob[(d8 + jj) * 68 + qq];
        hh[jj] = f2bf(v);
        ll[jj] = f2bf(v - bf2f(hh[jj]));
      }
      uint4 hp, lp;
      hp.x = hh[0] | ((uint)hh[1] << 16); hp.y = hh[2] | ((uint)hh[3] << 16);
      hp.z = hh[4] | ((uint)hh[5] << 16); hp.w = hh[6] | ((uint)hh[7] << 16);
      lp.x = ll[0] | ((uint)ll[1] << 16); lp.y = ll[2] | ((uint)ll[3] << 16);
      lp.z = ll[4] | ((uint)ll[5] << 16); lp.w = ll[6] | ((uint)ll[7] << 16);
      size_t rowb = (size_t)(b * 4096 + n0 + set * 64 + qq) * 1024 + h * 64 + d8;
      *(uint4*)(attno + rowb) = hp;
      *(uint4*)(attno + rowb + 512) = lp;
    }
  }
}

// ---------------- launch ----------------
extern "C" void kernel_launch(void* const* d_in, const int* in_sizes, int n_in,
                              void* d_out, int out_size, void* d_ws, size_t ws_size,
                              hipStream_t stream) {
  const float* x     = (const float*)d_in[0];
  const float* Wq    = (const float*)d_in[1];
  const float* bq    = (const float*)d_in[2];
  const float* Wk    = (const float*)d_in[3];
  const float* bk    = (const float*)d_in[4];
  const float* Wv    = (const float*)d_in[5];
  const float* bv    = (const float*)d_in[6];
  const float* Wp    = (const float*)d_in[7];
  const float* bp    = (const float*)d_in[8];
  const float* Wsr   = (const float*)d_in[9];
  const float* bsr   = (const float*)d_in[10];
  const float* gamma = (const float*)d_in[11];
  const float* beta  = (const float*)d_in[12];

  float* ws = (float*)d_ws;
  ushort* xq     = (ushort*)ws;
  ushort* attno_ = (ushort*)ws;
  float*  conv_part = ws + 8388608;
  ushort* Qsplit    = (ushort*)(ws + 8388608);
  ushort* Wsr_ = (ushort*)(ws + 16777216);
  float*  kvb  = ws + 20971520;
  ushort* Kq   = (ushort*)(ws + 22020096);
  ushort* Vt   = (ushort*)(ws + 22544384);
  ushort* Wq_  = (ushort*)(ws + 23068672);
  ushort* Wp_  = (ushort*)(ws + 23330816);
  ushort* Wkv_ = (ushort*)(ws + 23592960);
  ushort* xkv_ = (ushort*)(ws + 24117248);
  float*  bkv  = ws + 24641536;
  float* outp = (float*)d_out;

  prep_kernel<<<8705, 256, 0, stream>>>(x, Wq, Wp, Wk, Wv, Wsr, bk, bv,
                                        xq, Wq_, Wp_, Wkv_, Wsr_, bkv);
  conv_mfma_kernel<<<512, 256, 0, stream>>>(xq, Wsr_, conv_part);
  ln_kernel<<<1024, 256, 0, stream>>>(conv_part, bsr, gamma, beta, xkv_);
  proj_fused_kernel<<<576, 256, 0, stream>>>(xq, Wq_, bq, Qsplit, xkv_, Wkv_, bkv, kvb);
  kvprep_kernel<<<512, 256, 0, stream>>>(kvb, Kq, Vt);
  attn_kernel<<<dim3(32, 8, 4), 256, 0, stream>>>(Qsplit, Kq, Vt, attno_);
  gemm_out_kernel<<<512, 256, 0, stream>>>(attno_, Wp_, bp, outp);
}